// Round 16
// baseline (198.905 us; speedup 1.0000x reference)
//
#include <hip/hip_runtime.h>

static constexpr int N_NODES = 50000;
static constexpr int N_EDGES = 800000;
static constexpr int NPART = 8;               // XCD count
static constexpr int PART_SZ = N_NODES / NPART;  // 6250
static constexpr int NTILES = N_NODES / 16;   // 3125

typedef __attribute__((ext_vector_type(8))) short bf16x8;
typedef __attribute__((ext_vector_type(4))) float f32x4;

__device__ __forceinline__ float bf2f(unsigned short u) {
  union { unsigned int i; float f; } v; v.i = ((unsigned int)u) << 16; return v.f;
}
__device__ __forceinline__ unsigned short f2bf(float f) {
  union { unsigned int i; float f; } v; v.f = f;
  unsigned int r = (v.i + 0x7fffu + ((v.i >> 16) & 1u)) >> 16;
  return (unsigned short)r;
}
__device__ __forceinline__ int clampN(int v) {
  unsigned u = (unsigned)v; return (u < (unsigned)N_NODES) ? (int)u : 0;
}

__global__ void k_zero_out(float* __restrict__ out, int n) {
  int i = blockIdx.x * 256 + threadIdx.x;
  if (i < n) out[i] = 0.f;
}

// merged: compact (blocks 0..3124) | prepw (3125..3285) | zero deg/as1 (3286..3481)
__global__ void k_setup(const int* __restrict__ ei,
                        int* __restrict__ s32, int* __restrict__ d32,
                        const float* __restrict__ w1_src, const float* __restrict__ wlin,
                        const float* __restrict__ w2_src,
                        const float* __restrict__ w1_dst, const float* __restrict__ a1_dst,
                        const float* __restrict__ w2_dst, const float* __restrict__ a2_dst,
                        unsigned short* __restrict__ w1T, unsigned short* __restrict__ w2T,
                        float* __restrict__ c1dst, float* __restrict__ c2dst,
                        int* __restrict__ deg, float* __restrict__ as1) {
  int b = blockIdx.x;
  if (b < 3125) {
    int e = b * 256 + threadIdx.x;
    if (e < N_EDGES) {
      int z = ei[1] | ei[3] | ei[5] | ei[7];   // broadcast loads, L1-hit
      int f = (z == 0) ? 1 : 0;                // 1 => int64 storage
      s32[e] = clampN(ei[(size_t)e << f]);
      d32[e] = clampN(ei[(size_t)(N_EDGES + e) << f]);
    }
  } else if (b < 3286) {
    int idx = (b - 3125) * 256 + threadIdx.x;
    if (idx < 256 * 128) {
      int c = idx >> 7, k = idx & 127;
      float v = (c < 128) ? w1_src[k * 128 + c] : wlin[k * 128 + (c - 128)];
      w1T[idx] = f2bf(v);
    } else if (idx < 256 * 128 + 64 * 128) {
      int r = idx - 256 * 128;
      int c = r >> 7, k = r & 127;
      w2T[r] = f2bf(w2_src[k * 64 + c]);
    } else if (b == 3285) {
      int k = threadIdx.x;
      if (k < 128) {
        float s1 = 0.f;
        for (int c = 0; c < 128; ++c) s1 += w1_dst[k * 128 + c] * a1_dst[c];
        c1dst[k] = s1;
        float s2 = 0.f;
        for (int c = 0; c < 64; ++c) s2 += w2_dst[k * 64 + c] * a2_dst[c];
        c2dst[k] = s2;
      }
    }
  } else {
    int i = (b - 3286) * 256 + threadIdx.x;
    if (i < N_NODES) { deg[i] = 0; as1[i] = 0.f; }
  }
}

// x(fp32) -> xb(bf16), fused ad1 = x . c1dst (fp32-accurate). 16 lanes per row.
__global__ __launch_bounds__(256) void k_prepx(
    const float* __restrict__ x, const float* __restrict__ c1dst,
    unsigned short* __restrict__ xb, float* __restrict__ ad1) {
  int gid = blockIdx.x * 256 + threadIdx.x;
  int row = gid >> 4, sl = gid & 15;
  const float* p = x + (size_t)row * 128 + sl * 8;
  float4 a0 = *(const float4*)p;
  float4 a1 = *(const float4*)(p + 4);
  uint4 o;
  o.x = (unsigned)f2bf(a0.x) | ((unsigned)f2bf(a0.y) << 16);
  o.y = (unsigned)f2bf(a0.z) | ((unsigned)f2bf(a0.w) << 16);
  o.z = (unsigned)f2bf(a1.x) | ((unsigned)f2bf(a1.y) << 16);
  o.w = (unsigned)f2bf(a1.z) | ((unsigned)f2bf(a1.w) << 16);
  *(uint4*)(xb + (size_t)row * 128 + sl * 8) = o;
  float4 ca = *(const float4*)(c1dst + sl * 8);
  float4 cb = *(const float4*)(c1dst + sl * 8 + 4);
  float sd = a0.x * ca.x + a0.y * ca.y + a0.z * ca.z + a0.w * ca.w +
             a1.x * cb.x + a1.y * cb.y + a1.z * cb.z + a1.w * cb.w;
  sd += __shfl_xor(sd, 1, 64);
  sd += __shfl_xor(sd, 2, 64);
  sd += __shfl_xor(sd, 4, 64);
  sd += __shfl_xor(sd, 8, 64);
  if (sl == 0) ad1[row] = sd;
}

// Persistent-B swapped-operand MFMA GEMM1 + fused as1 (2 deterministic atomics/row).
__global__ __launch_bounds__(256) void k_gemm1(
    const unsigned short* __restrict__ xb, const unsigned short* __restrict__ w1T,
    const float* __restrict__ lin_b, const float* __restrict__ a1_src,
    unsigned short* __restrict__ hs1, unsigned short* __restrict__ linzb,
    float* __restrict__ as1) {
  int tid = threadIdx.x;
  int wv = tid >> 6, l = tid & 63;
  int lrow = l & 15, lk = l >> 4;
  int cb = wv * 64;                       // this wave's column chunk
  bf16x8 wfrag[4][4];
#pragma unroll
  for (int ct = 0; ct < 4; ++ct)
#pragma unroll
    for (int ks = 0; ks < 4; ++ks)
      wfrag[ct][ks] = *(const bf16x8*)(w1T + (size_t)(cb + ct * 16 + lrow) * 128 + ks * 32 + lk * 8);
  for (int t = blockIdx.x; t < NTILES; t += gridDim.x) {
    int row = t * 16 + lrow;
    bf16x8 xfrag[4];
#pragma unroll
    for (int ks = 0; ks < 4; ++ks)
      xfrag[ks] = *(const bf16x8*)(xb + (size_t)row * 128 + ks * 32 + lk * 8);
    f32x4 acc[4] = {{0.f,0.f,0.f,0.f},{0.f,0.f,0.f,0.f},{0.f,0.f,0.f,0.f},{0.f,0.f,0.f,0.f}};
#pragma unroll
    for (int ks = 0; ks < 4; ++ks)
#pragma unroll
      for (int ct = 0; ct < 4; ++ct)
        acc[ct] = __builtin_amdgcn_mfma_f32_16x16x32_bf16(wfrag[ct][ks], xfrag[ks], acc[ct], 0, 0, 0);
    if (cb < 128) {
      float pa = 0.f;
#pragma unroll
      for (int ct = 0; ct < 4; ++ct) {
        int col0 = cb + ct * 16 + lk * 4;
        float4 av = *(const float4*)(a1_src + col0);
        pa += acc[ct][0] * av.x + acc[ct][1] * av.y + acc[ct][2] * av.z + acc[ct][3] * av.w;
        uint2 pv;
        pv.x = (unsigned)f2bf(acc[ct][0]) | ((unsigned)f2bf(acc[ct][1]) << 16);
        pv.y = (unsigned)f2bf(acc[ct][2]) | ((unsigned)f2bf(acc[ct][3]) << 16);
        *(uint2*)(hs1 + (size_t)row * 128 + col0) = pv;
      }
      pa += __shfl_xor(pa, 16, 64);
      pa += __shfl_xor(pa, 32, 64);
      if (l < 16) atomicAdd(&as1[t * 16 + l], pa);   // 2 waves/row: commutative fp32, deterministic
    } else {
#pragma unroll
      for (int ct = 0; ct < 4; ++ct) {
        int col0 = cb - 128 + ct * 16 + lk * 4;
        float4 bv = *(const float4*)(lin_b + col0);
        uint2 pv;
        pv.x = (unsigned)f2bf(acc[ct][0] + bv.x) | ((unsigned)f2bf(acc[ct][1] + bv.y) << 16);
        pv.y = (unsigned)f2bf(acc[ct][2] + bv.z) | ((unsigned)f2bf(acc[ct][3] + bv.w) << 16);
        *(uint2*)(linzb + (size_t)row * 128 + col0) = pv;
      }
    }
  }
}

// Persistent-B swapped-operand MFMA GEMM2; fused as2/ad2.
__global__ __launch_bounds__(256) void k_gemm2(
    const unsigned short* __restrict__ zb, const unsigned short* __restrict__ w2T,
    const float* __restrict__ a2_src, const float* __restrict__ c2dst,
    unsigned short* __restrict__ hs2, float* __restrict__ as2, float* __restrict__ ad2) {
  int tid = threadIdx.x;
  int wv = tid >> 6, l = tid & 63;
  int lrow = l & 15, lk = l >> 4;
  int g = blockIdx.x * 4 + wv;
  if (g >= NTILES) return;
  bf16x8 wfrag[4][4];
#pragma unroll
  for (int ct = 0; ct < 4; ++ct)
#pragma unroll
    for (int ks = 0; ks < 4; ++ks)
      wfrag[ct][ks] = *(const bf16x8*)(w2T + (size_t)(ct * 16 + lrow) * 128 + ks * 32 + lk * 8);
  int row = g * 16 + lrow;
  bf16x8 xfrag[4];
  float sd = 0.f;
#pragma unroll
  for (int ks = 0; ks < 4; ++ks) {
    bf16x8 af = *(const bf16x8*)(zb + (size_t)row * 128 + ks * 32 + lk * 8);
    xfrag[ks] = af;
    int k0 = ks * 32 + lk * 8;
    float4 ca = *(const float4*)(c2dst + k0);
    float4 cb = *(const float4*)(c2dst + k0 + 4);
    sd += bf2f((unsigned short)af[0]) * ca.x + bf2f((unsigned short)af[1]) * ca.y +
          bf2f((unsigned short)af[2]) * ca.z + bf2f((unsigned short)af[3]) * ca.w +
          bf2f((unsigned short)af[4]) * cb.x + bf2f((unsigned short)af[5]) * cb.y +
          bf2f((unsigned short)af[6]) * cb.z + bf2f((unsigned short)af[7]) * cb.w;
  }
  sd += __shfl_xor(sd, 16, 64);
  sd += __shfl_xor(sd, 32, 64);
  if (lk == 0) ad2[row] = sd;

  f32x4 acc[4] = {{0.f,0.f,0.f,0.f},{0.f,0.f,0.f,0.f},{0.f,0.f,0.f,0.f},{0.f,0.f,0.f,0.f}};
#pragma unroll
  for (int ks = 0; ks < 4; ++ks)
#pragma unroll
    for (int ct = 0; ct < 4; ++ct)
      acc[ct] = __builtin_amdgcn_mfma_f32_16x16x32_bf16(wfrag[ct][ks], xfrag[ks], acc[ct], 0, 0, 0);
  float pa = 0.f;
#pragma unroll
  for (int ct = 0; ct < 4; ++ct) {
    int col0 = ct * 16 + lk * 4;
    float4 av = *(const float4*)(a2_src + col0);
    pa += acc[ct][0] * av.x + acc[ct][1] * av.y + acc[ct][2] * av.z + acc[ct][3] * av.w;
    uint2 pv;
    pv.x = (unsigned)f2bf(acc[ct][0]) | ((unsigned)f2bf(acc[ct][1]) << 16);
    pv.y = (unsigned)f2bf(acc[ct][2]) | ((unsigned)f2bf(acc[ct][3]) << 16);
    *(uint2*)(hs2 + (size_t)row * 64 + col0) = pv;
  }
  pa += __shfl_xor(pa, 16, 64);
  pa += __shfl_xor(pa, 32, 64);
  if (lk == 0) as2[row] = pa;
}

// XCD-partitioned count on compacted dst
__global__ void k_count(const int* __restrict__ d32, int* __restrict__ deg) {
  int part = blockIdx.x & (NPART - 1);
  int e = (blockIdx.x >> 3) * 256 + threadIdx.x;
  if (e < N_EDGES) {
    int d = d32[e];
    int lo = part * PART_SZ;
    if (d >= lo && d < lo + PART_SZ) atomicAdd(&deg[d], 1);
  }
}

__global__ __launch_bounds__(256) void k_scan1(const int* __restrict__ deg,
                                               int* __restrict__ offs,
                                               int* __restrict__ bsums, int n) {
  __shared__ int wsum[4];
  int i = blockIdx.x * 256 + threadIdx.x;
  int lane = threadIdx.x & 63, wid = threadIdx.x >> 6;
  int v = (i < n) ? deg[i] : 0;
  int s = v;
#pragma unroll
  for (int o = 1; o < 64; o <<= 1) { int t = __shfl_up(s, o, 64); if (lane >= o) s += t; }
  if (lane == 63) wsum[wid] = s;
  __syncthreads();
  if (threadIdx.x == 0) {
    int a = 0;
#pragma unroll
    for (int w = 0; w < 4; ++w) { a += wsum[w]; wsum[w] = a; }
  }
  __syncthreads();
  int base = (wid > 0) ? wsum[wid - 1] : 0;
  if (i < n) offs[i] = base + s - v;
  if (threadIdx.x == 0) bsums[blockIdx.x] = wsum[3];
}

__global__ __launch_bounds__(256) void k_scan2(int* __restrict__ bsums, int nb,
                                               int* __restrict__ offs, int n, int etot) {
  __shared__ int wsum[4];
  int tid = threadIdx.x, lane = tid & 63, wid = tid >> 6;
  int v = (tid < nb) ? bsums[tid] : 0;
  int s = v;
#pragma unroll
  for (int o = 1; o < 64; o <<= 1) { int t = __shfl_up(s, o, 64); if (lane >= o) s += t; }
  if (lane == 63) wsum[wid] = s;
  __syncthreads();
  if (tid == 0) {
    int a = 0;
#pragma unroll
    for (int w = 0; w < 4; ++w) { a += wsum[w]; wsum[w] = a; }
  }
  __syncthreads();
  int base = (wid > 0) ? wsum[wid - 1] : 0;
  if (tid < nb) bsums[tid] = base + s - v;
  if (tid == 0) offs[n] = etot;
}

__global__ __launch_bounds__(256) void k_scan3(int* __restrict__ offs, int* __restrict__ cursor,
                                               const int* __restrict__ bsums, int n) {
  int i = blockIdx.x * 256 + threadIdx.x;
  if (i < n) {
    int o = offs[i] + bsums[blockIdx.x];
    offs[i] = o;
    cursor[i] = o;
  }
}

// XCD-partitioned CSR fill on compacted arrays
__global__ void k_fill(const int* __restrict__ s32, const int* __restrict__ d32,
                       int* __restrict__ cursor, int* __restrict__ ssrc) {
  int part = blockIdx.x & (NPART - 1);
  int e = (blockIdx.x >> 3) * 256 + threadIdx.x;
  if (e < N_EDGES) {
    int d = d32[e];
    int lo = part * PART_SZ;
    if (d >= lo && d < lo + PART_SZ) {
      int p = atomicAdd(&cursor[d], 1);
      if ((unsigned)p < (unsigned)N_EDGES) ssrc[p] = s32[e];
    }
  }
}

// layer-1 agg: 4 slots x 16 lanes x 8 ch; gather pipeline 2-deep (loads 2 iters ahead)
__global__ __launch_bounds__(256) void k_agg1(
    const int* __restrict__ offs, const int* __restrict__ ssrc,
    const float* __restrict__ as_, const float* __restrict__ ad_,
    const unsigned short* __restrict__ hs1, const float* __restrict__ b1,
    unsigned short* __restrict__ linzb) {
  int node = (int)((blockIdx.x * 256 + threadIdx.x) >> 6);
  if (node >= N_NODES) return;
  int lane = threadIdx.x & 63;
  int g = lane >> 4, cl = lane & 15;
  int o0 = offs[node], o1 = offs[node + 1];
  if (!((unsigned)o0 <= (unsigned)N_EDGES && (unsigned)o1 <= (unsigned)N_EDGES && o0 <= o1))
    { o0 = 0; o1 = 0; }
  int deg = o1 - o0;
  float ad = ad_[node];
  float acc[8];
#pragma unroll
  for (int k = 0; k < 8; ++k) acc[k] = 0.f;
  float ssum = 0.f;
  // pipeline primers: A=cur, B=next fully loaded; C index prefetched
  int sA = (g < deg)     ? clampN(ssrc[o0 + g])     : 0;
  int sB = (g + 4 < deg) ? clampN(ssrc[o0 + g + 4]) : 0;
  int sC = (g + 8 < deg) ? clampN(ssrc[o0 + g + 8]) : 0;
  float asA = as_[sA], asB = as_[sB];
  uint4 hvA = *(const uint4*)(hs1 + (size_t)sA * 128 + cl * 8);
  uint4 hvB = *(const uint4*)(hs1 + (size_t)sB * 128 + cl * 8);
  for (int j = g; j < deg; j += 4) {
    int sD = (j + 12 < deg) ? clampN(ssrc[o0 + j + 12]) : 0;
    float asC = as_[sC];
    uint4 hvC = *(const uint4*)(hs1 + (size_t)sC * 128 + cl * 8);
    float e = asA + ad;
    e = e > 0.f ? e : 0.2f * e;
    float w = __expf(e);
    ssum += w;
    acc[0] += w * __uint_as_float(hvA.x << 16);
    acc[1] += w * __uint_as_float(hvA.x & 0xffff0000u);
    acc[2] += w * __uint_as_float(hvA.y << 16);
    acc[3] += w * __uint_as_float(hvA.y & 0xffff0000u);
    acc[4] += w * __uint_as_float(hvA.z << 16);
    acc[5] += w * __uint_as_float(hvA.z & 0xffff0000u);
    acc[6] += w * __uint_as_float(hvA.w << 16);
    acc[7] += w * __uint_as_float(hvA.w & 0xffff0000u);
    asA = asB; hvA = hvB;
    asB = asC; hvB = hvC;
    sC = sD;
  }
  ssum += __shfl_xor(ssum, 16, 64);
  ssum += __shfl_xor(ssum, 32, 64);
#pragma unroll
  for (int k = 0; k < 8; ++k) {
    acc[k] += __shfl_xor(acc[k], 16, 64);
    acc[k] += __shfl_xor(acc[k], 32, 64);
  }
  if (g == 0) {
    float inv = 1.f / (ssum + 1e-16f);
    uint4 lv = *(const uint4*)(linzb + (size_t)node * 128 + cl * 8);
    float4 ba = *(const float4*)(b1 + cl * 8);
    float4 bb = *(const float4*)(b1 + cl * 8 + 4);
    float z[8];
    z[0] = acc[0] * inv + ba.x + __uint_as_float(lv.x << 16);
    z[1] = acc[1] * inv + ba.y + __uint_as_float(lv.x & 0xffff0000u);
    z[2] = acc[2] * inv + ba.z + __uint_as_float(lv.y << 16);
    z[3] = acc[3] * inv + ba.w + __uint_as_float(lv.y & 0xffff0000u);
    z[4] = acc[4] * inv + bb.x + __uint_as_float(lv.z << 16);
    z[5] = acc[5] * inv + bb.y + __uint_as_float(lv.z & 0xffff0000u);
    z[6] = acc[6] * inv + bb.z + __uint_as_float(lv.w << 16);
    z[7] = acc[7] * inv + bb.w + __uint_as_float(lv.w & 0xffff0000u);
#pragma unroll
    for (int k = 0; k < 8; ++k) z[k] = z[k] > 0.f ? z[k] : 0.f;
    uint4 ov;
    ov.x = (unsigned)f2bf(z[0]) | ((unsigned)f2bf(z[1]) << 16);
    ov.y = (unsigned)f2bf(z[2]) | ((unsigned)f2bf(z[3]) << 16);
    ov.z = (unsigned)f2bf(z[4]) | ((unsigned)f2bf(z[5]) << 16);
    ov.w = (unsigned)f2bf(z[6]) | ((unsigned)f2bf(z[7]) << 16);
    *(uint4*)(linzb + (size_t)node * 128 + cl * 8) = ov;
  }
}

// layer-2 agg: 8 slots x 8 lanes x 8 ch; 2-deep gather pipeline; fp32 out (+b2)
__global__ __launch_bounds__(256) void k_agg2(
    const int* __restrict__ offs, const int* __restrict__ ssrc,
    const float* __restrict__ as_, const float* __restrict__ ad_,
    const unsigned short* __restrict__ hs2, const float* __restrict__ b2,
    float* __restrict__ out) {
  int node = (int)((blockIdx.x * 256 + threadIdx.x) >> 6);
  if (node >= N_NODES) return;
  int lane = threadIdx.x & 63;
  int g = lane >> 3, cl = lane & 7;
  int o0 = offs[node], o1 = offs[node + 1];
  if (!((unsigned)o0 <= (unsigned)N_EDGES && (unsigned)o1 <= (unsigned)N_EDGES && o0 <= o1))
    { o0 = 0; o1 = 0; }
  int deg = o1 - o0;
  float ad = ad_[node];
  float acc[8];
#pragma unroll
  for (int k = 0; k < 8; ++k) acc[k] = 0.f;
  float ssum = 0.f;
  int sA = (g < deg)      ? clampN(ssrc[o0 + g])      : 0;
  int sB = (g + 8 < deg)  ? clampN(ssrc[o0 + g + 8])  : 0;
  int sC = (g + 16 < deg) ? clampN(ssrc[o0 + g + 16]) : 0;
  float asA = as_[sA], asB = as_[sB];
  uint4 hvA = *(const uint4*)(hs2 + (size_t)sA * 64 + cl * 8);
  uint4 hvB = *(const uint4*)(hs2 + (size_t)sB * 64 + cl * 8);
  for (int j = g; j < deg; j += 8) {
    int sD = (j + 24 < deg) ? clampN(ssrc[o0 + j + 24]) : 0;
    float asC = as_[sC];
    uint4 hvC = *(const uint4*)(hs2 + (size_t)sC * 64 + cl * 8);
    float e = asA + ad;
    e = e > 0.f ? e : 0.2f * e;
    float w = __expf(e);
    ssum += w;
    acc[0] += w * __uint_as_float(hvA.x << 16);
    acc[1] += w * __uint_as_float(hvA.x & 0xffff0000u);
    acc[2] += w * __uint_as_float(hvA.y << 16);
    acc[3] += w * __uint_as_float(hvA.y & 0xffff0000u);
    acc[4] += w * __uint_as_float(hvA.z << 16);
    acc[5] += w * __uint_as_float(hvA.z & 0xffff0000u);
    acc[6] += w * __uint_as_float(hvA.w << 16);
    acc[7] += w * __uint_as_float(hvA.w & 0xffff0000u);
    asA = asB; hvA = hvB;
    asB = asC; hvB = hvC;
    sC = sD;
  }
  ssum += __shfl_xor(ssum, 8, 64);
  ssum += __shfl_xor(ssum, 16, 64);
  ssum += __shfl_xor(ssum, 32, 64);
#pragma unroll
  for (int k = 0; k < 8; ++k) {
    acc[k] += __shfl_xor(acc[k], 8, 64);
    acc[k] += __shfl_xor(acc[k], 16, 64);
    acc[k] += __shfl_xor(acc[k], 32, 64);
  }
  if (g == 0) {
    float inv = 1.f / (ssum + 1e-16f);
    float4 ba = *(const float4*)(b2 + cl * 8);
    float4 bb = *(const float4*)(b2 + cl * 8 + 4);
    float4 oa, ob;
    oa.x = acc[0] * inv + ba.x;
    oa.y = acc[1] * inv + ba.y;
    oa.z = acc[2] * inv + ba.z;
    oa.w = acc[3] * inv + ba.w;
    ob.x = acc[4] * inv + bb.x;
    ob.y = acc[5] * inv + bb.y;
    ob.z = acc[6] * inv + bb.z;
    ob.w = acc[7] * inv + bb.w;
    *(float4*)(out + (size_t)node * 64 + cl * 8) = oa;
    *(float4*)(out + (size_t)node * 64 + cl * 8 + 4) = ob;
  }
}

extern "C" void kernel_launch(void* const* d_in, const int* in_sizes, int n_in,
                              void* d_out, int out_size, void* d_ws, size_t ws_size,
                              hipStream_t stream) {
  (void)in_sizes; (void)n_in;
  const float* x      = (const float*)d_in[0];
  const int*   ei     = (const int*)d_in[1];
  const float* lin1_w = (const float*)d_in[2];
  const float* lin1_b = (const float*)d_in[3];
  const float* w1_src = (const float*)d_in[4];
  const float* w1_dst = (const float*)d_in[5];
  const float* a1_src = (const float*)d_in[6];
  const float* a1_dst = (const float*)d_in[7];
  const float* b1     = (const float*)d_in[8];
  const float* w2_src = (const float*)d_in[9];
  const float* w2_dst = (const float*)d_in[10];
  const float* a2_src = (const float*)d_in[11];
  const float* a2_dst = (const float*)d_in[12];
  const float* b2     = (const float*)d_in[13];
  float* out = (float*)d_out;

  char* ws = (char*)d_ws;
  size_t off = 0;
  auto alloc = [&](size_t bytes) -> void* {
    void* p = ws + off;
    off += (bytes + 255) & ~(size_t)255;
    return p;
  };
  float* c1dst = (float*)alloc(128 * 4);
  float* c2dst = (float*)alloc(128 * 4);
  unsigned short* w1T = (unsigned short*)alloc(256 * 128 * 2);
  unsigned short* w2T = (unsigned short*)alloc(64 * 128 * 2);
  int* deg     = (int*)alloc((size_t)N_NODES * 4);
  float* as1   = (float*)alloc((size_t)N_NODES * 4);
  int* offs    = (int*)alloc((size_t)(N_NODES + 1) * 4);
  int* cursor  = (int*)alloc((size_t)N_NODES * 4);
  int* bsums   = (int*)alloc(1024);
  float* ad1   = (float*)alloc((size_t)N_NODES * 4);
  int* s32     = (int*)alloc((size_t)N_EDGES * 4);
  int* d32     = (int*)alloc((size_t)N_EDGES * 4);
  unsigned short* hs1   = (unsigned short*)alloc((size_t)N_NODES * 128 * 2);
  unsigned short* linzb = (unsigned short*)alloc((size_t)N_NODES * 128 * 2);
  // Union region: xb (alive prepx..gemm1) overlaps {ssrc, hs2, as2, ad2} (alive fill..agg2)
  char* U = (char*)alloc((size_t)N_NODES * 128 * 2);   // 12.8 MB
  unsigned short* xb  = (unsigned short*)U;
  int* ssrc           = (int*)U;                                        // 3.2 MB
  unsigned short* hs2 = (unsigned short*)(U + (size_t)N_EDGES * 4);     // 6.4 MB
  float* as2          = (float*)(U + (size_t)N_EDGES * 4 + (size_t)N_NODES * 128);
  float* ad2          = (float*)(U + (size_t)N_EDGES * 4 + (size_t)N_NODES * 128 + (size_t)N_NODES * 4);

  if (off > ws_size) {
    k_zero_out<<<(out_size + 255) / 256, 256, 0, stream>>>(out, out_size);
    return;
  }

  int ebl8 = NPART * ((N_EDGES + 255) / 256);  // 25000
  int nbl  = (N_NODES + 3) / 4;                // 12500
  int nb   = (N_NODES + 255) / 256;            // 196
  k_setup<<<3482, 256, 0, stream>>>(ei, s32, d32, w1_src, lin1_w, w2_src,
                                    w1_dst, a1_dst, w2_dst, a2_dst,
                                    w1T, w2T, c1dst, c2dst, deg, as1);
  k_prepx<<<NTILES, 256, 0, stream>>>(x, c1dst, xb, ad1);
  k_gemm1<<<1024, 256, 0, stream>>>(xb, w1T, lin1_b, a1_src, hs1, linzb, as1);
  k_count<<<ebl8, 256, 0, stream>>>(d32, deg);
  k_scan1<<<nb, 256, 0, stream>>>(deg, offs, bsums, N_NODES);
  k_scan2<<<1, 256, 0, stream>>>(bsums, nb, offs, N_NODES, N_EDGES);
  k_scan3<<<nb, 256, 0, stream>>>(offs, cursor, bsums, N_NODES);
  k_fill<<<ebl8, 256, 0, stream>>>(s32, d32, cursor, ssrc);
  k_agg1<<<nbl, 256, 0, stream>>>(offs, ssrc, as1, ad1, hs1, b1, linzb);
  k_gemm2<<<(NTILES + 3) / 4, 256, 0, stream>>>(linzb, w2T, a2_src, c2dst, hs2, as2, ad2);
  k_agg2<<<nbl, 256, 0, stream>>>(offs, ssrc, as2, ad2, hs2, b2, out);
}

// Round 17
// 195.642 us; speedup vs baseline: 1.0167x; 1.0167x over previous
//
#include <hip/hip_runtime.h>

static constexpr int N_NODES = 50000;
static constexpr int N_EDGES = 800000;
static constexpr int NPART = 8;               // XCD count
static constexpr int PART_SZ = N_NODES / NPART;  // 6250
static constexpr int NTILES = N_NODES / 16;   // 3125

typedef __attribute__((ext_vector_type(8))) short bf16x8;
typedef __attribute__((ext_vector_type(4))) float f32x4;

__device__ __forceinline__ float bf2f(unsigned short u) {
  union { unsigned int i; float f; } v; v.i = ((unsigned int)u) << 16; return v.f;
}
__device__ __forceinline__ unsigned short f2bf(float f) {
  union { unsigned int i; float f; } v; v.f = f;
  unsigned int r = (v.i + 0x7fffu + ((v.i >> 16) & 1u)) >> 16;
  return (unsigned short)r;
}
__device__ __forceinline__ int clampN(int v) {
  unsigned u = (unsigned)v; return (u < (unsigned)N_NODES) ? (int)u : 0;
}

__global__ void k_zero_out(float* __restrict__ out, int n) {
  int i = blockIdx.x * 256 + threadIdx.x;
  if (i < n) out[i] = 0.f;
}

// merged: compact (blocks 0..3124) | prepw (3125..3285) | zero deg/as1 (3286..3481)
__global__ void k_setup(const int* __restrict__ ei,
                        int* __restrict__ s32, int* __restrict__ d32,
                        const float* __restrict__ w1_src, const float* __restrict__ wlin,
                        const float* __restrict__ w2_src,
                        const float* __restrict__ w1_dst, const float* __restrict__ a1_dst,
                        const float* __restrict__ w2_dst, const float* __restrict__ a2_dst,
                        unsigned short* __restrict__ w1T, unsigned short* __restrict__ w2T,
                        float* __restrict__ c1dst, float* __restrict__ c2dst,
                        int* __restrict__ deg, float* __restrict__ as1) {
  int b = blockIdx.x;
  if (b < 3125) {
    int e = b * 256 + threadIdx.x;
    if (e < N_EDGES) {
      int z = ei[1] | ei[3] | ei[5] | ei[7];   // broadcast loads, L1-hit
      int f = (z == 0) ? 1 : 0;                // 1 => int64 storage
      s32[e] = clampN(ei[(size_t)e << f]);
      d32[e] = clampN(ei[(size_t)(N_EDGES + e) << f]);
    }
  } else if (b < 3286) {
    int idx = (b - 3125) * 256 + threadIdx.x;
    if (idx < 256 * 128) {
      int c = idx >> 7, k = idx & 127;
      float v = (c < 128) ? w1_src[k * 128 + c] : wlin[k * 128 + (c - 128)];
      w1T[idx] = f2bf(v);
    } else if (idx < 256 * 128 + 64 * 128) {
      int r = idx - 256 * 128;
      int c = r >> 7, k = r & 127;
      w2T[r] = f2bf(w2_src[k * 64 + c]);
    } else if (b == 3285) {
      int k = threadIdx.x;
      if (k < 128) {
        float s1 = 0.f;
        for (int c = 0; c < 128; ++c) s1 += w1_dst[k * 128 + c] * a1_dst[c];
        c1dst[k] = s1;
        float s2 = 0.f;
        for (int c = 0; c < 64; ++c) s2 += w2_dst[k * 64 + c] * a2_dst[c];
        c2dst[k] = s2;
      }
    }
  } else {
    int i = (b - 3286) * 256 + threadIdx.x;
    if (i < N_NODES) { deg[i] = 0; as1[i] = 0.f; }
  }
}

// x(fp32) -> xb(bf16), fused ad1 = x . c1dst (fp32-accurate). 16 lanes per row.
__global__ __launch_bounds__(256) void k_prepx(
    const float* __restrict__ x, const float* __restrict__ c1dst,
    unsigned short* __restrict__ xb, float* __restrict__ ad1) {
  int gid = blockIdx.x * 256 + threadIdx.x;
  int row = gid >> 4, sl = gid & 15;
  const float* p = x + (size_t)row * 128 + sl * 8;
  float4 a0 = *(const float4*)p;
  float4 a1 = *(const float4*)(p + 4);
  uint4 o;
  o.x = (unsigned)f2bf(a0.x) | ((unsigned)f2bf(a0.y) << 16);
  o.y = (unsigned)f2bf(a0.z) | ((unsigned)f2bf(a0.w) << 16);
  o.z = (unsigned)f2bf(a1.x) | ((unsigned)f2bf(a1.y) << 16);
  o.w = (unsigned)f2bf(a1.z) | ((unsigned)f2bf(a1.w) << 16);
  *(uint4*)(xb + (size_t)row * 128 + sl * 8) = o;
  float4 ca = *(const float4*)(c1dst + sl * 8);
  float4 cb = *(const float4*)(c1dst + sl * 8 + 4);
  float sd = a0.x * ca.x + a0.y * ca.y + a0.z * ca.z + a0.w * ca.w +
             a1.x * cb.x + a1.y * cb.y + a1.z * cb.z + a1.w * cb.w;
  sd += __shfl_xor(sd, 1, 64);
  sd += __shfl_xor(sd, 2, 64);
  sd += __shfl_xor(sd, 4, 64);
  sd += __shfl_xor(sd, 8, 64);
  if (sl == 0) ad1[row] = sd;
}

// Persistent-B swapped-operand MFMA GEMM1 + fused as1 (2 deterministic atomics/row).
__global__ __launch_bounds__(256) void k_gemm1(
    const unsigned short* __restrict__ xb, const unsigned short* __restrict__ w1T,
    const float* __restrict__ lin_b, const float* __restrict__ a1_src,
    unsigned short* __restrict__ hs1, unsigned short* __restrict__ linzb,
    float* __restrict__ as1) {
  int tid = threadIdx.x;
  int wv = tid >> 6, l = tid & 63;
  int lrow = l & 15, lk = l >> 4;
  int cb = wv * 64;                       // this wave's column chunk
  bf16x8 wfrag[4][4];
#pragma unroll
  for (int ct = 0; ct < 4; ++ct)
#pragma unroll
    for (int ks = 0; ks < 4; ++ks)
      wfrag[ct][ks] = *(const bf16x8*)(w1T + (size_t)(cb + ct * 16 + lrow) * 128 + ks * 32 + lk * 8);
  for (int t = blockIdx.x; t < NTILES; t += gridDim.x) {
    int row = t * 16 + lrow;
    bf16x8 xfrag[4];
#pragma unroll
    for (int ks = 0; ks < 4; ++ks)
      xfrag[ks] = *(const bf16x8*)(xb + (size_t)row * 128 + ks * 32 + lk * 8);
    f32x4 acc[4] = {{0.f,0.f,0.f,0.f},{0.f,0.f,0.f,0.f},{0.f,0.f,0.f,0.f},{0.f,0.f,0.f,0.f}};
#pragma unroll
    for (int ks = 0; ks < 4; ++ks)
#pragma unroll
      for (int ct = 0; ct < 4; ++ct)
        acc[ct] = __builtin_amdgcn_mfma_f32_16x16x32_bf16(wfrag[ct][ks], xfrag[ks], acc[ct], 0, 0, 0);
    if (cb < 128) {
      float pa = 0.f;
#pragma unroll
      for (int ct = 0; ct < 4; ++ct) {
        int col0 = cb + ct * 16 + lk * 4;
        float4 av = *(const float4*)(a1_src + col0);
        pa += acc[ct][0] * av.x + acc[ct][1] * av.y + acc[ct][2] * av.z + acc[ct][3] * av.w;
        uint2 pv;
        pv.x = (unsigned)f2bf(acc[ct][0]) | ((unsigned)f2bf(acc[ct][1]) << 16);
        pv.y = (unsigned)f2bf(acc[ct][2]) | ((unsigned)f2bf(acc[ct][3]) << 16);
        *(uint2*)(hs1 + (size_t)row * 128 + col0) = pv;
      }
      pa += __shfl_xor(pa, 16, 64);
      pa += __shfl_xor(pa, 32, 64);
      if (l < 16) atomicAdd(&as1[t * 16 + l], pa);   // 2 waves/row: commutative fp32, deterministic
    } else {
#pragma unroll
      for (int ct = 0; ct < 4; ++ct) {
        int col0 = cb - 128 + ct * 16 + lk * 4;
        float4 bv = *(const float4*)(lin_b + col0);
        uint2 pv;
        pv.x = (unsigned)f2bf(acc[ct][0] + bv.x) | ((unsigned)f2bf(acc[ct][1] + bv.y) << 16);
        pv.y = (unsigned)f2bf(acc[ct][2] + bv.z) | ((unsigned)f2bf(acc[ct][3] + bv.w) << 16);
        *(uint2*)(linzb + (size_t)row * 128 + col0) = pv;
      }
    }
  }
}

// Persistent-B swapped-operand MFMA GEMM2; fused as2/ad2.
__global__ __launch_bounds__(256) void k_gemm2(
    const unsigned short* __restrict__ zb, const unsigned short* __restrict__ w2T,
    const float* __restrict__ a2_src, const float* __restrict__ c2dst,
    unsigned short* __restrict__ hs2, float* __restrict__ as2, float* __restrict__ ad2) {
  int tid = threadIdx.x;
  int wv = tid >> 6, l = tid & 63;
  int lrow = l & 15, lk = l >> 4;
  int g = blockIdx.x * 4 + wv;
  if (g >= NTILES) return;
  bf16x8 wfrag[4][4];
#pragma unroll
  for (int ct = 0; ct < 4; ++ct)
#pragma unroll
    for (int ks = 0; ks < 4; ++ks)
      wfrag[ct][ks] = *(const bf16x8*)(w2T + (size_t)(ct * 16 + lrow) * 128 + ks * 32 + lk * 8);
  int row = g * 16 + lrow;
  bf16x8 xfrag[4];
  float sd = 0.f;
#pragma unroll
  for (int ks = 0; ks < 4; ++ks) {
    bf16x8 af = *(const bf16x8*)(zb + (size_t)row * 128 + ks * 32 + lk * 8);
    xfrag[ks] = af;
    int k0 = ks * 32 + lk * 8;
    float4 ca = *(const float4*)(c2dst + k0);
    float4 cb = *(const float4*)(c2dst + k0 + 4);
    sd += bf2f((unsigned short)af[0]) * ca.x + bf2f((unsigned short)af[1]) * ca.y +
          bf2f((unsigned short)af[2]) * ca.z + bf2f((unsigned short)af[3]) * ca.w +
          bf2f((unsigned short)af[4]) * cb.x + bf2f((unsigned short)af[5]) * cb.y +
          bf2f((unsigned short)af[6]) * cb.z + bf2f((unsigned short)af[7]) * cb.w;
  }
  sd += __shfl_xor(sd, 16, 64);
  sd += __shfl_xor(sd, 32, 64);
  if (lk == 0) ad2[row] = sd;

  f32x4 acc[4] = {{0.f,0.f,0.f,0.f},{0.f,0.f,0.f,0.f},{0.f,0.f,0.f,0.f},{0.f,0.f,0.f,0.f}};
#pragma unroll
  for (int ks = 0; ks < 4; ++ks)
#pragma unroll
    for (int ct = 0; ct < 4; ++ct)
      acc[ct] = __builtin_amdgcn_mfma_f32_16x16x32_bf16(wfrag[ct][ks], xfrag[ks], acc[ct], 0, 0, 0);
  float pa = 0.f;
#pragma unroll
  for (int ct = 0; ct < 4; ++ct) {
    int col0 = ct * 16 + lk * 4;
    float4 av = *(const float4*)(a2_src + col0);
    pa += acc[ct][0] * av.x + acc[ct][1] * av.y + acc[ct][2] * av.z + acc[ct][3] * av.w;
    uint2 pv;
    pv.x = (unsigned)f2bf(acc[ct][0]) | ((unsigned)f2bf(acc[ct][1]) << 16);
    pv.y = (unsigned)f2bf(acc[ct][2]) | ((unsigned)f2bf(acc[ct][3]) << 16);
    *(uint2*)(hs2 + (size_t)row * 64 + col0) = pv;
  }
  pa += __shfl_xor(pa, 16, 64);
  pa += __shfl_xor(pa, 32, 64);
  if (lk == 0) as2[row] = pa;
}

// XCD-partitioned count on compacted dst
__global__ void k_count(const int* __restrict__ d32, int* __restrict__ deg) {
  int part = blockIdx.x & (NPART - 1);
  int e = (blockIdx.x >> 3) * 256 + threadIdx.x;
  if (e < N_EDGES) {
    int d = d32[e];
    int lo = part * PART_SZ;
    if (d >= lo && d < lo + PART_SZ) atomicAdd(&deg[d], 1);
  }
}

__global__ __launch_bounds__(256) void k_scan1(const int* __restrict__ deg,
                                               int* __restrict__ offs,
                                               int* __restrict__ bsums, int n) {
  __shared__ int wsum[4];
  int i = blockIdx.x * 256 + threadIdx.x;
  int lane = threadIdx.x & 63, wid = threadIdx.x >> 6;
  int v = (i < n) ? deg[i] : 0;
  int s = v;
#pragma unroll
  for (int o = 1; o < 64; o <<= 1) { int t = __shfl_up(s, o, 64); if (lane >= o) s += t; }
  if (lane == 63) wsum[wid] = s;
  __syncthreads();
  if (threadIdx.x == 0) {
    int a = 0;
#pragma unroll
    for (int w = 0; w < 4; ++w) { a += wsum[w]; wsum[w] = a; }
  }
  __syncthreads();
  int base = (wid > 0) ? wsum[wid - 1] : 0;
  if (i < n) offs[i] = base + s - v;
  if (threadIdx.x == 0) bsums[blockIdx.x] = wsum[3];
}

__global__ __launch_bounds__(256) void k_scan2(int* __restrict__ bsums, int nb,
                                               int* __restrict__ offs, int n, int etot) {
  __shared__ int wsum[4];
  int tid = threadIdx.x, lane = tid & 63, wid = tid >> 6;
  int v = (tid < nb) ? bsums[tid] : 0;
  int s = v;
#pragma unroll
  for (int o = 1; o < 64; o <<= 1) { int t = __shfl_up(s, o, 64); if (lane >= o) s += t; }
  if (lane == 63) wsum[wid] = s;
  __syncthreads();
  if (tid == 0) {
    int a = 0;
#pragma unroll
    for (int w = 0; w < 4; ++w) { a += wsum[w]; wsum[w] = a; }
  }
  __syncthreads();
  int base = (wid > 0) ? wsum[wid - 1] : 0;
  if (tid < nb) bsums[tid] = base + s - v;
  if (tid == 0) offs[n] = etot;
}

__global__ __launch_bounds__(256) void k_scan3(int* __restrict__ offs, int* __restrict__ cursor,
                                               const int* __restrict__ bsums, int n) {
  int i = blockIdx.x * 256 + threadIdx.x;
  if (i < n) {
    int o = offs[i] + bsums[blockIdx.x];
    offs[i] = o;
    cursor[i] = o;
  }
}

// XCD-partitioned CSR fill on compacted arrays
__global__ void k_fill(const int* __restrict__ s32, const int* __restrict__ d32,
                       int* __restrict__ cursor, int* __restrict__ ssrc) {
  int part = blockIdx.x & (NPART - 1);
  int e = (blockIdx.x >> 3) * 256 + threadIdx.x;
  if (e < N_EDGES) {
    int d = d32[e];
    int lo = part * PART_SZ;
    if (d >= lo && d < lo + PART_SZ) {
      int p = atomicAdd(&cursor[d], 1);
      if ((unsigned)p < (unsigned)N_EDGES) ssrc[p] = s32[e];
    }
  }
}

// layer-1 agg: 4 slots x 16 lanes x 8 ch; gather pipeline 1-deep (proven best)
__global__ __launch_bounds__(256) void k_agg1(
    const int* __restrict__ offs, const int* __restrict__ ssrc,
    const float* __restrict__ as_, const float* __restrict__ ad_,
    const unsigned short* __restrict__ hs1, const float* __restrict__ b1,
    unsigned short* __restrict__ linzb) {
  int node = (int)((blockIdx.x * 256 + threadIdx.x) >> 6);
  if (node >= N_NODES) return;
  int lane = threadIdx.x & 63;
  int g = lane >> 4, cl = lane & 15;
  int o0 = offs[node], o1 = offs[node + 1];
  if (!((unsigned)o0 <= (unsigned)N_EDGES && (unsigned)o1 <= (unsigned)N_EDGES && o0 <= o1))
    { o0 = 0; o1 = 0; }
  int deg = o1 - o0;
  float ad = ad_[node];
  float acc[8];
#pragma unroll
  for (int k = 0; k < 8; ++k) acc[k] = 0.f;
  float ssum = 0.f;
  // pipeline primers: current (j=g) fully loaded; next index prefetched
  int s_nx = (g + 4 < deg) ? clampN(ssrc[o0 + g + 4]) : 0;
  int s_cu = (g < deg) ? clampN(ssrc[o0 + g]) : 0;
  float as_cu = as_[s_cu];
  uint4 hv_cu = *(const uint4*)(hs1 + (size_t)s_cu * 128 + cl * 8);
  for (int j = g; j < deg; j += 4) {
    int s_n2 = (j + 8 < deg) ? clampN(ssrc[o0 + j + 8]) : 0;
    float as_nx = as_[s_nx];
    uint4 hv_nx = *(const uint4*)(hs1 + (size_t)s_nx * 128 + cl * 8);
    float e = as_cu + ad;
    e = e > 0.f ? e : 0.2f * e;
    float w = __expf(e);
    ssum += w;
    acc[0] += w * __uint_as_float(hv_cu.x << 16);
    acc[1] += w * __uint_as_float(hv_cu.x & 0xffff0000u);
    acc[2] += w * __uint_as_float(hv_cu.y << 16);
    acc[3] += w * __uint_as_float(hv_cu.y & 0xffff0000u);
    acc[4] += w * __uint_as_float(hv_cu.z << 16);
    acc[5] += w * __uint_as_float(hv_cu.z & 0xffff0000u);
    acc[6] += w * __uint_as_float(hv_cu.w << 16);
    acc[7] += w * __uint_as_float(hv_cu.w & 0xffff0000u);
    s_nx = s_n2;
    as_cu = as_nx;
    hv_cu = hv_nx;
  }
  ssum += __shfl_xor(ssum, 16, 64);
  ssum += __shfl_xor(ssum, 32, 64);
#pragma unroll
  for (int k = 0; k < 8; ++k) {
    acc[k] += __shfl_xor(acc[k], 16, 64);
    acc[k] += __shfl_xor(acc[k], 32, 64);
  }
  if (g == 0) {
    float inv = 1.f / (ssum + 1e-16f);
    uint4 lv = *(const uint4*)(linzb + (size_t)node * 128 + cl * 8);
    float4 ba = *(const float4*)(b1 + cl * 8);
    float4 bb = *(const float4*)(b1 + cl * 8 + 4);
    float z[8];
    z[0] = acc[0] * inv + ba.x + __uint_as_float(lv.x << 16);
    z[1] = acc[1] * inv + ba.y + __uint_as_float(lv.x & 0xffff0000u);
    z[2] = acc[2] * inv + ba.z + __uint_as_float(lv.y << 16);
    z[3] = acc[3] * inv + ba.w + __uint_as_float(lv.y & 0xffff0000u);
    z[4] = acc[4] * inv + bb.x + __uint_as_float(lv.z << 16);
    z[5] = acc[5] * inv + bb.y + __uint_as_float(lv.z & 0xffff0000u);
    z[6] = acc[6] * inv + bb.z + __uint_as_float(lv.w << 16);
    z[7] = acc[7] * inv + bb.w + __uint_as_float(lv.w & 0xffff0000u);
#pragma unroll
    for (int k = 0; k < 8; ++k) z[k] = z[k] > 0.f ? z[k] : 0.f;
    uint4 ov;
    ov.x = (unsigned)f2bf(z[0]) | ((unsigned)f2bf(z[1]) << 16);
    ov.y = (unsigned)f2bf(z[2]) | ((unsigned)f2bf(z[3]) << 16);
    ov.z = (unsigned)f2bf(z[4]) | ((unsigned)f2bf(z[5]) << 16);
    ov.w = (unsigned)f2bf(z[6]) | ((unsigned)f2bf(z[7]) << 16);
    *(uint4*)(linzb + (size_t)node * 128 + cl * 8) = ov;
  }
}

// layer-2 agg: 8 slots x 8 lanes x 8 ch; 1-deep gather pipeline; fp32 out (+b2)
__global__ __launch_bounds__(256) void k_agg2(
    const int* __restrict__ offs, const int* __restrict__ ssrc,
    const float* __restrict__ as_, const float* __restrict__ ad_,
    const unsigned short* __restrict__ hs2, const float* __restrict__ b2,
    float* __restrict__ out) {
  int node = (int)((blockIdx.x * 256 + threadIdx.x) >> 6);
  if (node >= N_NODES) return;
  int lane = threadIdx.x & 63;
  int g = lane >> 3, cl = lane & 7;
  int o0 = offs[node], o1 = offs[node + 1];
  if (!((unsigned)o0 <= (unsigned)N_EDGES && (unsigned)o1 <= (unsigned)N_EDGES && o0 <= o1))
    { o0 = 0; o1 = 0; }
  int deg = o1 - o0;
  float ad = ad_[node];
  float acc[8];
#pragma unroll
  for (int k = 0; k < 8; ++k) acc[k] = 0.f;
  float ssum = 0.f;
  int s_nx = (g + 8 < deg) ? clampN(ssrc[o0 + g + 8]) : 0;
  int s_cu = (g < deg) ? clampN(ssrc[o0 + g]) : 0;
  float as_cu = as_[s_cu];
  uint4 hv_cu = *(const uint4*)(hs2 + (size_t)s_cu * 64 + cl * 8);
  for (int j = g; j < deg; j += 8) {
    int s_n2 = (j + 16 < deg) ? clampN(ssrc[o0 + j + 16]) : 0;
    float as_nx = as_[s_nx];
    uint4 hv_nx = *(const uint4*)(hs2 + (size_t)s_nx * 64 + cl * 8);
    float e = as_cu + ad;
    e = e > 0.f ? e : 0.2f * e;
    float w = __expf(e);
    ssum += w;
    acc[0] += w * __uint_as_float(hv_cu.x << 16);
    acc[1] += w * __uint_as_float(hv_cu.x & 0xffff0000u);
    acc[2] += w * __uint_as_float(hv_cu.y << 16);
    acc[3] += w * __uint_as_float(hv_cu.y & 0xffff0000u);
    acc[4] += w * __uint_as_float(hv_cu.z << 16);
    acc[5] += w * __uint_as_float(hv_cu.z & 0xffff0000u);
    acc[6] += w * __uint_as_float(hv_cu.w << 16);
    acc[7] += w * __uint_as_float(hv_cu.w & 0xffff0000u);
    s_nx = s_n2;
    as_cu = as_nx;
    hv_cu = hv_nx;
  }
  ssum += __shfl_xor(ssum, 8, 64);
  ssum += __shfl_xor(ssum, 16, 64);
  ssum += __shfl_xor(ssum, 32, 64);
#pragma unroll
  for (int k = 0; k < 8; ++k) {
    acc[k] += __shfl_xor(acc[k], 8, 64);
    acc[k] += __shfl_xor(acc[k], 16, 64);
    acc[k] += __shfl_xor(acc[k], 32, 64);
  }
  if (g == 0) {
    float inv = 1.f / (ssum + 1e-16f);
    float4 ba = *(const float4*)(b2 + cl * 8);
    float4 bb = *(const float4*)(b2 + cl * 8 + 4);
    float4 oa, ob;
    oa.x = acc[0] * inv + ba.x;
    oa.y = acc[1] * inv + ba.y;
    oa.z = acc[2] * inv + ba.z;
    oa.w = acc[3] * inv + ba.w;
    ob.x = acc[4] * inv + bb.x;
    ob.y = acc[5] * inv + bb.y;
    ob.z = acc[6] * inv + bb.z;
    ob.w = acc[7] * inv + bb.w;
    *(float4*)(out + (size_t)node * 64 + cl * 8) = oa;
    *(float4*)(out + (size_t)node * 64 + cl * 8 + 4) = ob;
  }
}

extern "C" void kernel_launch(void* const* d_in, const int* in_sizes, int n_in,
                              void* d_out, int out_size, void* d_ws, size_t ws_size,
                              hipStream_t stream) {
  (void)in_sizes; (void)n_in;
  const float* x      = (const float*)d_in[0];
  const int*   ei     = (const int*)d_in[1];
  const float* lin1_w = (const float*)d_in[2];
  const float* lin1_b = (const float*)d_in[3];
  const float* w1_src = (const float*)d_in[4];
  const float* w1_dst = (const float*)d_in[5];
  const float* a1_src = (const float*)d_in[6];
  const float* a1_dst = (const float*)d_in[7];
  const float* b1     = (const float*)d_in[8];
  const float* w2_src = (const float*)d_in[9];
  const float* w2_dst = (const float*)d_in[10];
  const float* a2_src = (const float*)d_in[11];
  const float* a2_dst = (const float*)d_in[12];
  const float* b2     = (const float*)d_in[13];
  float* out = (float*)d_out;

  char* ws = (char*)d_ws;
  size_t off = 0;
  auto alloc = [&](size_t bytes) -> void* {
    void* p = ws + off;
    off += (bytes + 255) & ~(size_t)255;
    return p;
  };
  float* c1dst = (float*)alloc(128 * 4);
  float* c2dst = (float*)alloc(128 * 4);
  unsigned short* w1T = (unsigned short*)alloc(256 * 128 * 2);
  unsigned short* w2T = (unsigned short*)alloc(64 * 128 * 2);
  int* deg     = (int*)alloc((size_t)N_NODES * 4);
  float* as1   = (float*)alloc((size_t)N_NODES * 4);
  int* offs    = (int*)alloc((size_t)(N_NODES + 1) * 4);
  int* cursor  = (int*)alloc((size_t)N_NODES * 4);
  int* bsums   = (int*)alloc(1024);
  float* ad1   = (float*)alloc((size_t)N_NODES * 4);
  int* s32     = (int*)alloc((size_t)N_EDGES * 4);
  int* d32     = (int*)alloc((size_t)N_EDGES * 4);
  unsigned short* hs1   = (unsigned short*)alloc((size_t)N_NODES * 128 * 2);
  unsigned short* linzb = (unsigned short*)alloc((size_t)N_NODES * 128 * 2);
  // Union region: xb (alive prepx..gemm1) overlaps {ssrc, hs2, as2, ad2} (alive fill..agg2)
  char* U = (char*)alloc((size_t)N_NODES * 128 * 2);   // 12.8 MB
  unsigned short* xb  = (unsigned short*)U;
  int* ssrc           = (int*)U;                                        // 3.2 MB
  unsigned short* hs2 = (unsigned short*)(U + (size_t)N_EDGES * 4);     // 6.4 MB
  float* as2          = (float*)(U + (size_t)N_EDGES * 4 + (size_t)N_NODES * 128);
  float* ad2          = (float*)(U + (size_t)N_EDGES * 4 + (size_t)N_NODES * 128 + (size_t)N_NODES * 4);

  if (off > ws_size) {
    k_zero_out<<<(out_size + 255) / 256, 256, 0, stream>>>(out, out_size);
    return;
  }

  int ebl8 = NPART * ((N_EDGES + 255) / 256);  // 25000
  int nbl  = (N_NODES + 3) / 4;                // 12500
  int nb   = (N_NODES + 255) / 256;            // 196
  k_setup<<<3482, 256, 0, stream>>>(ei, s32, d32, w1_src, lin1_w, w2_src,
                                    w1_dst, a1_dst, w2_dst, a2_dst,
                                    w1T, w2T, c1dst, c2dst, deg, as1);
  k_prepx<<<NTILES, 256, 0, stream>>>(x, c1dst, xb, ad1);
  k_gemm1<<<1024, 256, 0, stream>>>(xb, w1T, lin1_b, a1_src, hs1, linzb, as1);
  k_count<<<ebl8, 256, 0, stream>>>(d32, deg);
  k_scan1<<<nb, 256, 0, stream>>>(deg, offs, bsums, N_NODES);
  k_scan2<<<1, 256, 0, stream>>>(bsums, nb, offs, N_NODES, N_EDGES);
  k_scan3<<<nb, 256, 0, stream>>>(offs, cursor, bsums, N_NODES);
  k_fill<<<ebl8, 256, 0, stream>>>(s32, d32, cursor, ssrc);
  k_agg1<<<nbl, 256, 0, stream>>>(offs, ssrc, as1, ad1, hs1, b1, linzb);
  k_gemm2<<<(NTILES + 3) / 4, 256, 0, stream>>>(linzb, w2T, a2_src, c2dst, hs2, as2, ad2);
  k_agg2<<<nbl, 256, 0, stream>>>(offs, ssrc, as2, ad2, hs2, b2, out);
}